// Round 6
// baseline (450.824 us; speedup 1.0000x reference)
//
#include <hip/hip_runtime.h>

#define TPB 256
#define HWSZ 9216      // 96*96

typedef __attribute__((ext_vector_type(8))) short short8x;
typedef __attribute__((ext_vector_type(4))) float f32x4;
typedef unsigned short ushort_t;
typedef unsigned int uint_t;

__device__ __forceinline__ float sigf(float v) { return 1.0f / (1.0f + __expf(-v)); }

__device__ __forceinline__ ushort_t f2bf(float f) {
  uint_t u = __float_as_uint(f);
  u = (u + 0x7fffu + ((u >> 16) & 1u)) >> 16;
  return (ushort_t)u;
}
__device__ __forceinline__ float bf2f(ushort_t h) {
  return __uint_as_float(((uint_t)h) << 16);
}

// fp32 epilogue-LDS swizzle (1024B rows): bijective, conflict-free columns
__device__ __forceinline__ int swz32(int p, int c) {
  return p * 1024 + ((((c * 4) ^ ((p & 7) << 4)) ^ (((p >> 3) & 3) << 2)));
}

// ---------------- pack weights to fragment-major bf16 ----------------
// B-frag tile(kt,nt): elem(l,j) = B[kt*32+(l>>4)*8+j][col(nt,l&15)], 1KB each
// Gp:  [dir4][kt8][nt16][64][8]
// Ftp: [kt8][nt16][64][8]
// W1p: [jc4][kt8][nt16][64][8], nt even: a-col jc*128+(nt>>1)*16+llo,
//                               nt odd : g-col 512+jc*128+(nt>>1)*16+llo
// W2p: [kt16][nt16][64][8]
__global__ __launch_bounds__(TPB) void k_pack(
    const float* __restrict__ lrg, const float* __restrict__ rlg,
    const float* __restrict__ tbg, const float* __restrict__ btg,
    const float* __restrict__ fusew, const float* __restrict__ ff1w,
    const float* __restrict__ ff2w,
    ushort_t* __restrict__ Gp, ushort_t* __restrict__ Ftp,
    ushort_t* __restrict__ W1p, ushort_t* __restrict__ W2p) {
  int i = blockIdx.x * TPB + threadIdx.x;
  if (i < 262144) {
    int d = i >> 16, r = i & 65535;
    int kt = r >> 13, nt = (r >> 9) & 15, l = (r >> 3) & 63, j = r & 7;
    int k = kt * 32 + (l >> 4) * 8 + j;
    int n_ = nt * 16 + (l & 15);
    const float* g = (d == 0) ? lrg : (d == 1) ? rlg : (d == 2) ? tbg : btg;
    Gp[i] = f2bf(g[n_ * 256 + k]);
  } else if (i < 327680) {
    int r = i - 262144;
    int kt = r >> 13, nt = (r >> 9) & 15, l = (r >> 3) & 63, j = r & 7;
    int k = kt * 32 + (l >> 4) * 8 + j;
    int n_ = nt * 16 + (l & 15);
    Ftp[r] = f2bf(fusew[n_ * 256 + k]);
  } else if (i < 589824) {
    int r = i - 327680;
    int jc = r >> 16, kt = (r >> 13) & 7, nt = (r >> 9) & 15, l = (r >> 3) & 63, j = r & 7;
    int k = kt * 32 + (l >> 4) * 8 + j;
    int base = jc * 128 + (nt >> 1) * 16 + (l & 15);
    int col = (nt & 1) ? (512 + base) : base;
    W1p[r] = f2bf(ff1w[col * 256 + k]);
  } else if (i < 720896) {
    int r = i - 589824;
    int kt = r >> 13, nt = (r >> 9) & 15, l = (r >> 3) & 63, j = r & 7;
    int k = kt * 32 + (l >> 4) * 8 + j;
    int n_ = nt * 16 + (l & 15);
    W2p[r] = f2bf(ff2w[n_ * 512 + k]);
  }
}

// ---------------- per-(n,c) LayerNorm2d stats ----------------
__global__ __launch_bounds__(TPB) void k_stats(const float* __restrict__ src,
                                               float* __restrict__ mean,
                                               float* __restrict__ rstd) {
  int nc = blockIdx.x;
  const float* p = src + (long)nc * HWSZ;
  float s = 0.f, s2 = 0.f;
  for (int i = threadIdx.x; i < HWSZ; i += TPB) {
    float v = p[i];
    s += v;
    s2 = fmaf(v, v, s2);
  }
#pragma unroll
  for (int off = 32; off > 0; off >>= 1) {
    s += __shfl_down(s, off);
    s2 += __shfl_down(s2, off);
  }
  __shared__ float ls[4], ls2[4];
  int lane = threadIdx.x & 63, wv = threadIdx.x >> 6;
  if (lane == 0) { ls[wv] = s; ls2[wv] = s2; }
  __syncthreads();
  if (threadIdx.x == 0) {
    float S = ls[0] + ls[1] + ls[2] + ls[3];
    float S2 = ls2[0] + ls2[1] + ls2[2] + ls2[3];
    float m = S * (1.0f / HWSZ);
    float var = S2 * (1.0f / HWSZ) - m * m;
    mean[nc] = m;
    rstd[nc] = rsqrtf(fmaxf(var, 0.f) + 1e-6f);
  }
}

// ---------------- ln1 + depthwise 3x3 -> y (NHWC bf16) ----------------
__global__ __launch_bounds__(TPB) void k_lndw(
    const float* __restrict__ x, const float* __restrict__ mean1,
    const float* __restrict__ rstd1, const float* __restrict__ ln1w,
    const float* __restrict__ ln1b, const float* __restrict__ dww,
    const float* __restrict__ dwb, ushort_t* __restrict__ y) {
  __shared__ float xl[3][32][101];
  int tid = threadIdx.x;
  int bid = blockIdx.x;
  int cb = (bid & 7) * 32;
  int h = (bid >> 3) % 96;
  int n = bid / 768;

  if (tid < 192) {
    int col = (tid & 1) ? 97 : 0;
    int rc = tid >> 1;
    xl[rc >> 5][rc & 31][col] = 0.f;
  }
  for (int i = tid; i < 3 * 32 * 96; i += TPB) {
    int w = i % 96;
    int rc = i / 96;
    int cc = rc & 31, rr = rc >> 5;
    int hh = h + rr - 1;
    float v = 0.f;
    if (hh >= 0 && hh < 96) {
      int c = cb + cc;
      int nc = n * 256 + c;
      float xv = x[(long)nc * HWSZ + hh * 96 + w];
      v = (xv - mean1[nc]) * rstd1[nc] * ln1w[c] + ln1b[c];
    }
    xl[rr][cc][w + 1] = v;
  }
  __syncthreads();

  int cc = tid & 31, wg = tid >> 5;
  int c = cb + cc;
  float wgt[9];
#pragma unroll
  for (int t = 0; t < 9; ++t) wgt[t] = dww[t * 256 + c];
  float bias = dwb[c];
  for (int wi = 0; wi < 12; ++wi) {
    int w = wg * 12 + wi;
    float acc = bias;
#pragma unroll
    for (int kh = 0; kh < 3; ++kh)
#pragma unroll
      for (int kw = 0; kw < 3; ++kw)
        acc = fmaf(xl[kh][cc][w + kw], wgt[kh * 3 + kw], acc);
    y[((long)(n * 96 + h) * 96 + w) * 256 + c] = f2bf(acc);
  }
}

// ---------------- scan pair: gate GEMM (B from L2) + dwconv1d*sigmoid --------
// Block = 48-pixel half-line. 8 waves, wave w owns nt {w*2, w*2+1}; mf=3.
template <int VERT>
__global__ __launch_bounds__(512, 4) void k_scan(
    const ushort_t* __restrict__ y, const ushort_t* __restrict__ Gp,
    const float* __restrict__ dwaw, const float* __restrict__ dwab,
    const float* __restrict__ gab, const float* __restrict__ dwbw,
    const float* __restrict__ dwbb, const float* __restrict__ gbb,
    ushort_t* __restrict__ o) {
  __shared__ __align__(16) char pool[51200];
  char* ylds = pool;            // 52 rows x 512B, swizzled (pixel q at row q-p0+2)
  char* olds = pool + 26624;    // 48 rows x 512B, swizzled

  int tid = threadIdx.x;
  int bid = blockIdx.x;
  int seg = bid & 1, line = (bid >> 1) % 96, n = bid / 192;
  int p0 = seg * 48;

  for (int u = tid; u < 52 * 32; u += 512) {
    int r = u >> 5, ks = u & 31;
    int q = p0 - 2 + r;
    uint4 v = make_uint4(0, 0, 0, 0);
    if (q >= 0 && q < 96) {
      long pix = VERT ? ((long)(n * 96 + q) * 96 + line)
                      : ((long)(n * 96 + line) * 96 + q);
      v = *(const uint4*)(y + pix * 256 + ks * 8);
    }
    *(uint4*)(ylds + r * 512 + ((ks * 16) ^ ((r & 7) << 4))) = v;
  }
  __syncthreads();

  int l = tid & 63, w = tid >> 6;
  int llo = l & 15, lhi = l >> 4;

  const uint4* gp4 = (const uint4*)Gp;
  float part[3][2][4];

#pragma unroll
  for (int diri = 0; diri < 2; ++diri) {
    int dir = VERT * 2 + diri;
    f32x4 acc[3][2];
#pragma unroll
    for (int mf = 0; mf < 3; ++mf)
#pragma unroll
      for (int ntl = 0; ntl < 2; ++ntl) acc[mf][ntl] = (f32x4){0.f, 0.f, 0.f, 0.f};

    const uint4* gbase = gp4 + ((long)(dir * 8) * 16 + w * 2) * 64 + l;
    short8x bc0 = *(const short8x*)(gbase);
    short8x bc1 = *(const short8x*)(gbase + 64);
#pragma unroll
    for (int kt = 0; kt < 8; ++kt) {
      short8x bn0, bn1;
      if (kt < 7) {
        bn0 = *(const short8x*)(gbase + (kt + 1) * 1024);
        bn1 = *(const short8x*)(gbase + (kt + 1) * 1024 + 64);
      }
      short8x a[3];
#pragma unroll
      for (int mf = 0; mf < 3; ++mf) {
        int arow = 2 + mf * 16 + llo;
        a[mf] = *(const short8x*)(ylds + arow * 512 +
                                  ((kt * 64 + lhi * 16) ^ ((arow & 7) << 4)));
      }
#pragma unroll
      for (int mf = 0; mf < 3; ++mf) {
        acc[mf][0] = __builtin_amdgcn_mfma_f32_16x16x32_bf16(a[mf], bc0, acc[mf][0], 0, 0, 0);
        acc[mf][1] = __builtin_amdgcn_mfma_f32_16x16x32_bf16(a[mf], bc1, acc[mf][1], 0, 0, 0);
      }
      bc0 = bn0;
      bc1 = bn1;
    }

    const float* dwv = diri ? dwbw : dwaw;
    const float* dbv = diri ? dwbb : dwab;
    const float* gbv = diri ? gbb : gab;
#pragma unroll
    for (int ntl = 0; ntl < 2; ++ntl) {
      int c = (w * 2 + ntl) * 16 + llo;
      float wt[5];
#pragma unroll
      for (int t = 0; t < 5; ++t)
        wt[t] = diri ? dwv[(4 - t) * 256 + c] : dwv[t * 256 + c];
      float cb = dbv[c], gb = gbv[c];
#pragma unroll
      for (int mf = 0; mf < 3; ++mf) {
        int pbase = mf * 16 + lhi * 4;
        float yv[8];
#pragma unroll
        for (int t = 0; t < 8; ++t) {
          int ry = pbase + t;
          yv[t] = bf2f(*(const ushort_t*)(ylds + ry * 512 +
                                          ((c * 2) ^ ((ry & 7) << 4))));
        }
#pragma unroll
        for (int r = 0; r < 4; ++r) {
          float conv = cb;
#pragma unroll
          for (int t = 0; t < 5; ++t) conv = fmaf(yv[r + t], wt[t], conv);
          float val = conv * sigf(acc[mf][ntl][r] + gb);
          if (diri == 0) {
            part[mf][ntl][r] = val;
          } else {
            int p = pbase + r;
            *(ushort_t*)(olds + p * 512 + ((c * 2) ^ ((p & 7) << 4))) =
                f2bf(part[mf][ntl][r] + val);
          }
        }
      }
    }
  }
  __syncthreads();

  for (int u = tid; u < 48 * 32; u += 512) {
    int p = u >> 5, ks = u & 31;
    uint4 v = *(const uint4*)(olds + p * 512 + ((ks * 16) ^ ((p & 7) << 4)));
    long pix = VERT ? ((long)(n * 96 + p0 + p) * 96 + line)
                    : ((long)(n * 96 + line) * 96 + p0 + p);
    ushort_t* dst = o + pix * 256 + ks * 8;
    if (VERT) {
      uint4 old = *(uint4*)dst;
      ushort_t* a8 = (ushort_t*)&v;
      ushort_t* b8 = (ushort_t*)&old;
#pragma unroll
      for (int j = 0; j < 8; ++j) a8[j] = f2bf(bf2f(a8[j]) + bf2f(b8[j]));
      *(uint4*)dst = v;
    } else {
      *(uint4*)dst = v;
    }
  }
}

// ---------------- fuse GEMM + residual: out(NCHW) = x + o@Ft + b ----------------
// M=64/block, 8 waves, wave w owns nt {w*2, w*2+1}; mf=4.
__global__ __launch_bounds__(512, 4) void k_fuse(
    const ushort_t* __restrict__ o, const ushort_t* __restrict__ Ftp,
    const float* __restrict__ fuseb, const float* __restrict__ x,
    float* __restrict__ out) {
  __shared__ __align__(16) char pool[32768];
  // pool = alds: 64 x 512B bf16 swizzled; epilogue reuses as 32 x 1024B f32

  int tid = threadIdx.x;
  int pix0 = blockIdx.x * 64;
  int n = pix0 / HWSZ, hw0 = pix0 % HWSZ;

  for (int u = tid; u < 64 * 32; u += 512) {
    int r = u >> 5, ks = u & 31;
    uint4 v = *(const uint4*)(o + (long)(pix0 + r) * 256 + ks * 8);
    *(uint4*)(pool + r * 512 + ((ks * 16) ^ ((r & 7) << 4))) = v;
  }
  __syncthreads();

  int l = tid & 63, w = tid >> 6;
  int llo = l & 15, lhi = l >> 4;

  const uint4* fp4 = (const uint4*)Ftp;
  f32x4 acc[4][2];
#pragma unroll
  for (int mf = 0; mf < 4; ++mf)
#pragma unroll
    for (int ntl = 0; ntl < 2; ++ntl) acc[mf][ntl] = (f32x4){0.f, 0.f, 0.f, 0.f};

  const uint4* fbase = fp4 + (long)(w * 2) * 64 + l;
  short8x bc0 = *(const short8x*)(fbase);
  short8x bc1 = *(const short8x*)(fbase + 64);
#pragma unroll
  for (int kt = 0; kt < 8; ++kt) {
    short8x bn0, bn1;
    if (kt < 7) {
      bn0 = *(const short8x*)(fbase + (kt + 1) * 1024);
      bn1 = *(const short8x*)(fbase + (kt + 1) * 1024 + 64);
    }
    short8x a[4];
#pragma unroll
    for (int mf = 0; mf < 4; ++mf) {
      int arow = mf * 16 + llo;
      a[mf] = *(const short8x*)(pool + arow * 512 +
                                ((kt * 64 + lhi * 16) ^ ((arow & 7) << 4)));
    }
#pragma unroll
    for (int mf = 0; mf < 4; ++mf) {
      acc[mf][0] = __builtin_amdgcn_mfma_f32_16x16x32_bf16(a[mf], bc0, acc[mf][0], 0, 0, 0);
      acc[mf][1] = __builtin_amdgcn_mfma_f32_16x16x32_bf16(a[mf], bc1, acc[mf][1], 0, 0, 0);
    }
    bc0 = bn0;
    bc1 = bn1;
  }
  __syncthreads();  // alds reads done -> reuse as f32 epilogue

  // epilogue: 2 chunks of 32 rows (chunk q = mf {2q, 2q+1})
  for (int q = 0; q < 2; ++q) {
#pragma unroll
    for (int mq = 0; mq < 2; ++mq) {
#pragma unroll
      for (int ntl = 0; ntl < 2; ++ntl) {
        int c = (w * 2 + ntl) * 16 + llo;
        float fb = fuseb[c];
#pragma unroll
        for (int r = 0; r < 4; ++r) {
          int p = mq * 16 + lhi * 4 + r;
          *(float*)(pool + swz32(p, c)) =
              (q == 0 ? acc[mq][ntl][r] : acc[2 + mq][ntl][r]) + fb;
        }
      }
    }
    __syncthreads();
    for (int i = tid; i < 8192; i += 512) {
      int c = i >> 5, p = i & 31;
      long addr = (long)(n * 256 + c) * HWSZ + hw0 + q * 32 + p;
      out[addr] = x[addr] + *(const float*)(pool + swz32(p, c));
    }
    __syncthreads();
  }
}

// ---------------- ln2 + ff1 + GLU + ff2 + residual (out +=) ----------------
// M=64/block, 8 waves; wave w = GLU pair-block w (GEMM1), nt {w*2,w*2+1} (GEMM2); mf=4.
__global__ __launch_bounds__(512, 4) void k_ff(
    const float* __restrict__ xres, const float* __restrict__ mean2,
    const float* __restrict__ rstd2, const float* __restrict__ ln2w,
    const float* __restrict__ ln2b, const ushort_t* __restrict__ W1p,
    const float* __restrict__ ff1b, const ushort_t* __restrict__ W2p,
    const float* __restrict__ ff2b, float* __restrict__ out) {
  __shared__ __align__(16) char pool[49152];
  char* hA = pool;              // 64 x 512B bf16, swizzled; epilogue reuses as f32
  char* uC = pool + 32768;      // 64 x 256B bf16, swizzled

  int tid = threadIdx.x;
  int pix0 = blockIdx.x * 64;
  int n = pix0 / HWSZ, hw0 = pix0 % HWSZ;

  for (int i = tid; i < 16384; i += 512) {
    int c = i >> 6, p = i & 63;
    int nc = n * 256 + c;
    float v = xres[(long)nc * HWSZ + hw0 + p];
    float hv = (v - mean2[nc]) * rstd2[nc] * ln2w[c] + ln2b[c];
    *(ushort_t*)(hA + p * 512 + ((c * 2) ^ ((p & 7) << 4))) = f2bf(hv);
  }
  __syncthreads();

  int l = tid & 63, w = tid >> 6;
  int llo = l & 15, lhi = l >> 4;

  const uint4* W1p4 = (const uint4*)W1p;
  const uint4* W2p4 = (const uint4*)W2p;

  f32x4 zacc[4][2];
#pragma unroll
  for (int mf = 0; mf < 4; ++mf)
#pragma unroll
    for (int ntl = 0; ntl < 2; ++ntl) zacc[mf][ntl] = (f32x4){0.f, 0.f, 0.f, 0.f};

  for (int jc = 0; jc < 4; ++jc) {
    // ---- GEMM1 chunk: wave w -> pair-block w (nt w*2 = a, w*2+1 = g)
    f32x4 ca[4][2];
#pragma unroll
    for (int mf = 0; mf < 4; ++mf)
#pragma unroll
      for (int ntl = 0; ntl < 2; ++ntl) ca[mf][ntl] = (f32x4){0.f, 0.f, 0.f, 0.f};

    const uint4* w1base = W1p4 + ((long)(jc * 8) * 16 + w * 2) * 64 + l;
    short8x bc0 = *(const short8x*)(w1base);
    short8x bc1 = *(const short8x*)(w1base + 64);
#pragma unroll
    for (int kt = 0; kt < 8; ++kt) {
      short8x bn0, bn1;
      if (kt < 7) {
        bn0 = *(const short8x*)(w1base + (kt + 1) * 1024);
        bn1 = *(const short8x*)(w1base + (kt + 1) * 1024 + 64);
      }
      short8x a[4];
#pragma unroll
      for (int mf = 0; mf < 4; ++mf) {
        int arow = mf * 16 + llo;
        a[mf] = *(const short8x*)(hA + arow * 512 +
                                  ((kt * 64 + lhi * 16) ^ ((arow & 7) << 4)));
      }
#pragma unroll
      for (int mf = 0; mf < 4; ++mf) {
        ca[mf][0] = __builtin_amdgcn_mfma_f32_16x16x32_bf16(a[mf], bc0, ca[mf][0], 0, 0, 0);
        ca[mf][1] = __builtin_amdgcn_mfma_f32_16x16x32_bf16(a[mf], bc1, ca[mf][1], 0, 0, 0);
      }
      bc0 = bn0;
      bc1 = bn1;
    }

    // ---- GLU: pair-block w -> uC cols w*16..w*16+15
    {
      int cacol = jc * 128 + w * 16 + llo;
      float ba = ff1b[cacol], bg = ff1b[512 + cacol];
      int cu = w * 16 + llo;
#pragma unroll
      for (int mf = 0; mf < 4; ++mf)
#pragma unroll
        for (int r = 0; r < 4; ++r) {
          float av = ca[mf][0][r] + ba;
          float gv = ca[mf][1][r] + bg;
          int p = mf * 16 + lhi * 4 + r;
          *(ushort_t*)(uC + p * 256 + ((cu * 2) ^ ((p & 7) << 4))) =
              f2bf(av * sigf(gv));
        }
    }
    __syncthreads();

    // ---- GEMM2 partial: K-chunk jc (4 kt2), wave w -> nt {w*2, w*2+1}
    const uint4* w2base = W2p4 + ((long)(jc * 4) * 16 + w * 2) * 64 + l;
    short8x b2c0 = *(const short8x*)(w2base);
    short8x b2c1 = *(const short8x*)(w2base + 64);
#pragma unroll
    for (int kt2 = 0; kt2 < 4; ++kt2) {
      short8x b2n0, b2n1;
      if (kt2 < 3) {
        b2n0 = *(const short8x*)(w2base + (kt2 + 1) * 1024);
        b2n1 = *(const short8x*)(w2base + (kt2 + 1) * 1024 + 64);
      }
      short8x a2[4];
#pragma unroll
      for (int mf = 0; mf < 4; ++mf) {
        int arow = mf * 16 + llo;
        a2[mf] = *(const short8x*)(uC + arow * 256 +
                                   ((kt2 * 64 + lhi * 16) ^ ((arow & 7) << 4)));
      }
#pragma unroll
      for (int mf = 0; mf < 4; ++mf) {
        zacc[mf][0] = __builtin_amdgcn_mfma_f32_16x16x32_bf16(a2[mf], b2c0, zacc[mf][0], 0, 0, 0);
        zacc[mf][1] = __builtin_amdgcn_mfma_f32_16x16x32_bf16(a2[mf], b2c1, zacc[mf][1], 0, 0, 0);
      }
      b2c0 = b2n0;
      b2c1 = b2n1;
    }
    __syncthreads();
  }

  // ---- epilogue: 2 chunks of 32 rows, reuse hA as f32 swz32 buffer
  for (int q = 0; q < 2; ++q) {
#pragma unroll
    for (int mq = 0; mq < 2; ++mq) {
#pragma unroll
      for (int ntl = 0; ntl < 2; ++ntl) {
        int c = (w * 2 + ntl) * 16 + llo;
        float fb = ff2b[c];
#pragma unroll
        for (int r = 0; r < 4; ++r) {
          int p = mq * 16 + lhi * 4 + r;
          *(float*)(hA + swz32(p, c)) =
              (q == 0 ? zacc[mq][ntl][r] : zacc[2 + mq][ntl][r]) + fb;
        }
      }
    }
    __syncthreads();
    for (int i = tid; i < 8192; i += 512) {
      int c = i >> 5, p = i & 31;
      long addr = (long)(n * 256 + c) * HWSZ + hw0 + q * 32 + p;
      out[addr] += *(const float*)(hA + swz32(p, c));
    }
    __syncthreads();
  }
}

extern "C" void kernel_launch(void* const* d_in, const int* in_sizes, int n_in,
                              void* d_out, int out_size, void* d_ws, size_t ws_size,
                              hipStream_t stream) {
  (void)in_sizes; (void)n_in; (void)out_size; (void)ws_size;
  const float* x     = (const float*)d_in[0];
  const float* ln1w  = (const float*)d_in[1];
  const float* ln1b  = (const float*)d_in[2];
  const float* dww   = (const float*)d_in[3];
  const float* dwb   = (const float*)d_in[4];
  const float* lr_w  = (const float*)d_in[5];
  const float* lr_b  = (const float*)d_in[6];
  const float* lr_gw = (const float*)d_in[7];
  const float* lr_gb = (const float*)d_in[8];
  const float* rl_w  = (const float*)d_in[9];
  const float* rl_b  = (const float*)d_in[10];
  const float* rl_gw = (const float*)d_in[11];
  const float* rl_gb = (const float*)d_in[12];
  const float* tb_w  = (const float*)d_in[13];
  const float* tb_b  = (const float*)d_in[14];
  const float* tb_gw = (const float*)d_in[15];
  const float* tb_gb = (const float*)d_in[16];
  const float* bt_w  = (const float*)d_in[17];
  const float* bt_b  = (const float*)d_in[18];
  const float* bt_gw = (const float*)d_in[19];
  const float* bt_gb = (const float*)d_in[20];
  const float* fusew = (const float*)d_in[21];
  const float* fuseb = (const float*)d_in[22];
  const float* ln2w  = (const float*)d_in[23];
  const float* ln2b  = (const float*)d_in[24];
  const float* ff1w  = (const float*)d_in[25];
  const float* ff1b  = (const float*)d_in[26];
  const float* ff2w  = (const float*)d_in[27];
  const float* ff2b  = (const float*)d_in[28];

  float* out = (float*)d_out;
  ushort_t* y = (ushort_t*)d_ws;                  // 18874368 bf16
  ushort_t* o = y + 18874368;                     // 18874368 bf16
  float* mean1 = (float*)(o + 18874368);
  float* rstd1 = mean1 + 2048;
  float* mean2 = rstd1 + 2048;
  float* rstd2 = mean2 + 2048;
  ushort_t* Gp  = (ushort_t*)(rstd2 + 2048);      // 262144
  ushort_t* Ftp = Gp + 262144;                    // 65536
  ushort_t* W1p = Ftp + 65536;                    // 262144
  ushort_t* W2p = W1p + 262144;                   // 131072

  k_pack<<<2816, TPB, 0, stream>>>(lr_gw, rl_gw, tb_gw, bt_gw, fusew, ff1w, ff2w,
                                   Gp, Ftp, W1p, W2p);
  k_stats<<<2048, TPB, 0, stream>>>(x, mean1, rstd1);
  k_lndw<<<6144, TPB, 0, stream>>>(x, mean1, rstd1, ln1w, ln1b, dww, dwb, y);
  k_scan<0><<<1536, 512, 0, stream>>>(y, Gp, lr_w, lr_b, lr_gb, rl_w, rl_b, rl_gb, o);
  k_scan<1><<<1536, 512, 0, stream>>>(y, Gp, tb_w, tb_b, tb_gb, bt_w, bt_b, bt_gb, o);
  k_fuse<<<1152, 512, 0, stream>>>(o, Ftp, fuseb, x, out);
  k_stats<<<2048, TPB, 0, stream>>>(out, mean2, rstd2);
  k_ff<<<1152, 512, 0, stream>>>(out, mean2, rstd2, ln2w, ln2b, W1p, ff1b,
                                 W2p, ff2b, out);
}